// Round 3
// baseline (104.571 us; speedup 1.0000x reference)
//
#include <hip/hip_runtime.h>

#define NQ 16384
#define NB 128
#define NF 64
#define HD 128
#define EPSF 1e-8f
#define BTILE 8
#define NBT (NB / BTILE)   // 16 btiles
#define NFP (NF / 2)       // 32 f-pairs

typedef float f32x2 __attribute__((ext_vector_type(2)));
typedef float f32x4 __attribute__((ext_vector_type(4)));

// Half-row: one f-pair, FOUR b's. 160 B contiguous. Two halves per fp.
// tab layout: [NBT][NFP][2 halves]; per-bt table = 32*320 B = 10240 B.
struct FRowH {
    f32x2 x[4];   // -2*P_real   for (f, f+1)
    f32x2 y[4];   // -2*P_imag
    f32x2 z[4];   // |P|^2 + eps
    f32x2 w[4];   // -softplus(qw)
    f32x2 m[4];   // magnitude weight
};

// ---------- prep: qvals planes (blocks 0..2047) + table (2048..2079) --------
// qA[fp*NQ + q] = (Qr_2fp, Qr_2fp+1, Qi_2fp, Qi_2fp+1)
// qB[fp*NQ + q] = (B0, B1, |Q|mag0, |Q|mag1)
__global__ __launch_bounds__(256) void prep_kernel(
    const float* __restrict__ Q,        // [NQ][HD]
    const float* __restrict__ probes,   // [NB][HD]
    const float* __restrict__ angles,   // [NF]
    const float* __restrict__ qw,       // [NB][NF]
    const float* __restrict__ mw,       // [NB][NF]
    f32x4* __restrict__ qA,             // [NFP][NQ]
    f32x4* __restrict__ qB,             // [NFP][NQ]
    FRowH* __restrict__ tab) {          // [NBT][NFP][2]
    __shared__ f32x4 sA[8][NFP + 1];
    __shared__ f32x4 sB[8][NFP + 1];
    if (blockIdx.x < 2048) {
        // 8 q per block, half-wave (32 lanes) per q; lane sl owns f-pair sl.
        const int qi = threadIdx.x >> 5;
        const int sl = threadIdx.x & 31;
        const int q  = blockIdx.x * 8 + qi;
        const float2* Q2 = (const float2*)Q;
        float2 a = Q2[q * 64 + sl];        // Qr[2sl], Qr[2sl+1]
        float2 c = Q2[q * 64 + 32 + sl];   // Qi[2sl], Qi[2sl+1]
        float ss = a.x * a.x + a.y * a.y + c.x * c.x + c.y * c.y;
        #pragma unroll
        for (int m = 1; m < 32; m <<= 1) ss += __shfl_xor(ss, m);  // half-wave
        float inv = 1.0f / (sqrtf(ss) + EPSF);
        float Qr0 = a.x * inv, Qr1 = a.y * inv;
        float Qi0 = c.x * inv, Qi1 = c.y * inv;
        float B0 = Qr0 * Qr0 + Qi0 * Qi0;
        float B1 = Qr1 * Qr1 + Qi1 * Qi1;
        f32x4 Av; Av.x = Qr0; Av.y = Qr1; Av.z = Qi0; Av.w = Qi1;
        f32x4 Bv; Bv.x = B0;  Bv.y = B1;
        Bv.z = sqrtf(B0 + EPSF); Bv.w = sqrtf(B1 + EPSF);
        sA[qi][sl] = Av;
        sB[qi][sl] = Bv;
        __syncthreads();
        // transposed write-out: 8 consecutive lanes write 128 B contiguous
        const int sl2 = threadIdx.x >> 3;   // f-pair
        const int qi2 = threadIdx.x & 7;    // q within block
        const int qb  = blockIdx.x * 8;
        qA[sl2 * NQ + qb + qi2] = sA[qi2][sl2];
        qB[sl2 * NQ + qb + qi2] = sB[qi2][sl2];
    } else {
        // table: 1 b per wave, lane = f (scatter stores; 32 blocks, negligible)
        const int b = (blockIdx.x - 2048) * 4 + (threadIdx.x >> 6);
        const int f = threadIdx.x & 63;
        float p0 = probes[b * HD + f];
        float p1 = probes[b * HD + 64 + f];
        float ss = p0 * p0 + p1 * p1;
        #pragma unroll
        for (int m = 1; m < 64; m <<= 1) ss += __shfl_xor(ss, m);
        float inv = 1.0f / (sqrtf(ss) + EPSF);
        float pr = p0 * inv, pi = p1 * inv;
        float ang = angles[f];
        float cc = cosf(ang), sn = sinf(ang);
        float Pr = pr * cc - pi * sn;
        float Pi = pr * sn + pi * cc;
        float x = qw[b * NF + f];
        float sp = (x > 0.0f) ? (x + log1pf(expf(-x))) : log1pf(expf(x));
        const int bt = b >> 3, bb = b & 7;
        const int h  = bb >> 2, bi = bb & 3;
        const int fp = f >> 1,  hi = f & 1;
        FRowH* r = &tab[(bt * NFP + fp) * 2 + h];
        ((float*)&r->x[bi])[hi] = -2.0f * Pr;
        ((float*)&r->y[bi])[hi] = -2.0f * Pi;
        ((float*)&r->z[bi])[hi] = Pr * Pr + Pi * Pi + EPSF;
        ((float*)&r->w[bi])[hi] = -sp;
        ((float*)&r->m[bi])[hi] = mw[b * NF + f];
    }
}

// ---------- main kernel ----------
// Table staged to LDS once per block (10.2 KB). Inner-loop table reads are
// ds_read_b64 from a wave-uniform base with compile-time offsets -> broadcast,
// conflict-free, and the compiler issues them AHEAD of the packed VALU with
// counted lgkmcnt (unlike the round-1/2 s_load chain, which serialized every
// fp iteration behind lgkmcnt(0) with only ~4 waves/SIMD to hide it).
__global__ __launch_bounds__(256, 4) void main_kernel(
    const FRowH* __restrict__ tab,      // [NBT][NFP][2]
    const f32x4* __restrict__ qA,       // [NFP][NQ]
    const f32x4* __restrict__ qB,       // [NFP][NQ]
    const float* __restrict__ bias,     // [NB]
    float* __restrict__ out) {          // [NQ][NB]
    __shared__ float4 ltab[640];        // 10240 B = one bt's table
    // XCD-bijective swizzle: all 16 bt-blocks of one q-chunk on ONE XCD.
    const int p    = blockIdx.x;
    const int xcd  = p & 7;
    const int j    = p >> 3;                 // 0..127 per XCD
    const int qblk = xcd * 8 + (j >> 4);     // 0..63
    const int bt   = j & 15;
    const int q    = qblk * 256 + threadIdx.x;

    // stage this bt's table into LDS (coalesced 16 B/lane)
    const float4* ts = (const float4*)(tab + bt * (NFP * 2));
    #pragma unroll
    for (int i = 0; i < 3; ++i) {
        int idx = threadIdx.x + i * 256;
        if (idx < 640) ltab[idx] = ts[idx];
    }
    __syncthreads();
    const char* lb = (const char*)ltab;

    f32x2 acc[BTILE];
    #pragma unroll
    for (int i = 0; i < BTILE; ++i) acc[i] = 0.0f;

    // one-iteration register prefetch of the coalesced q-planes
    f32x4 A = qA[q];            // fp = 0
    f32x4 B = qB[q];
    #pragma unroll 2
    for (int fp = 0; fp < NFP; ++fp) {
        const int fpn = (fp < NFP - 1) ? fp + 1 : fp;
        f32x4 An = qA[fpn * NQ + q];
        f32x4 Bn = qB[fpn * NQ + q];
        f32x2 qr2 = __builtin_shufflevector(A, A, 0, 1);
        f32x2 qi2 = __builtin_shufflevector(A, A, 2, 3);
        f32x2 qz2 = __builtin_shufflevector(B, B, 0, 1);
        f32x2 qm2 = __builtin_shufflevector(B, B, 2, 3);
        const char* rb = lb + fp * 320;      // uniform VGPR base, offsets imm
        #pragma unroll
        for (int h = 0; h < 2; ++h) {
            const char* rh = rb + h * 160;
            #pragma unroll
            for (int bi = 0; bi < 4; ++bi) {
                const int bb = h * 4 + bi;
                f32x2 tx = *(const f32x2*)(rh + bi * 8);        // ds_read_b64
                f32x2 ty = *(const f32x2*)(rh + 32 + bi * 8);
                f32x2 tz = *(const f32x2*)(rh + 64 + bi * 8);
                f32x2 tw = *(const f32x2*)(rh + 96 + bi * 8);
                f32x2 tm = *(const f32x2*)(rh + 128 + bi * 8);
                f32x2 t = tz + qz2;                             // v_pk_add_f32
                t = __builtin_elementwise_fma(ty, qi2, t);      // v_pk_fma_f32
                t = __builtin_elementwise_fma(tx, qr2, t);
                f32x2 d;
                d.x = __builtin_amdgcn_sqrtf(__builtin_fabsf(t.x)); // |t| = src mod
                d.y = __builtin_amdgcn_sqrtf(__builtin_fabsf(t.y));
                acc[bb] = __builtin_elementwise_fma(tw, d, acc[bb]);
                acc[bb] = __builtin_elementwise_fma(tm, qm2, acc[bb]);
            }
        }
        A = An; B = Bn;
    }

    float o[BTILE];
    #pragma unroll
    for (int bb = 0; bb < BTILE; ++bb)
        o[bb] = acc[bb].x + acc[bb].y + bias[bt * BTILE + bb];
    float* op = out + (size_t)q * NB + bt * BTILE;
    *(float4*)op       = make_float4(o[0], o[1], o[2], o[3]);
    *(float4*)(op + 4) = make_float4(o[4], o[5], o[6], o[7]);
}

extern "C" void kernel_launch(void* const* d_in, const int* in_sizes, int n_in,
                              void* d_out, int out_size, void* d_ws, size_t ws_size,
                              hipStream_t stream) {
    const float* Q      = (const float*)d_in[0];   // [16384][128]
    const float* angles = (const float*)d_in[1];   // [64]
    const float* probes = (const float*)d_in[2];   // [128][128]
    const float* qw     = (const float*)d_in[3];   // [128][64]
    const float* mw     = (const float*)d_in[4];   // [128][64]
    const float* bias   = (const float*)d_in[5];   // [128]
    float* out = (float*)d_out;

    char* ws = (char*)d_ws;
    FRowH* tab = (FRowH*)ws;                                     // 160 KB
    f32x4* qA  = (f32x4*)(ws + NBT * NFP * 2 * sizeof(FRowH));   // 8 MB
    f32x4* qB  = qA + (size_t)NFP * NQ;                          // 8 MB

    prep_kernel<<<2048 + NB / 4, 256, 0, stream>>>(Q, probes, angles, qw, mw, qA, qB, tab);
    main_kernel<<<(NQ / 256) * NBT, 256, 0, stream>>>(tab, qA, qB, bias, out);
}

// Round 4
// 99.211 us; speedup vs baseline: 1.0540x; 1.0540x over previous
//
#include <hip/hip_runtime.h>

#define NQ 16384
#define NB 128
#define NF 64
#define HD 128
#define EPSF 1e-8f
#define BTILE 8
#define NBT (NB / BTILE)   // 16 btiles
#define NFP (NF / 2)       // 32 f-pairs

typedef float f32x2 __attribute__((ext_vector_type(2)));
typedef float f32x4 __attribute__((ext_vector_type(4)));

// Packed-pair table row for one (btile, f-pair): SoA of f32x2 over the 8 b's.
// 320 B contiguous; wave-uniform address -> scalarized s_loads; every packed
// VOP has exactly 1 SGPR-pair operand. (Round-1 structure: best measured.)
struct FP2Row {
    f32x2 x2[BTILE];   // -2*P_real   for (f, f+1)
    f32x2 y2[BTILE];   // -2*P_imag
    f32x2 z2[BTILE];   // |P|^2 + eps
    f32x2 w2[BTILE];   // -softplus(qw)
    f32x2 m2[BTILE];   // magnitude weight
};

// ---------- prep: qA plane (blocks 0..2047) + table (2048..2079) ------------
// qA[fp*NQ + q] = (Qr_2fp, Qr_2fp+1, Qi_2fp, Qi_2fp+1)
// NOTE: no qB plane anymore -- B = Qr^2+Qi^2 and mag = sqrt(B+eps) are
// recomputed in-register by main (halves main's streamed bytes, which were
// saturating the per-CU L2-return port at ~57 B/cyc).
__global__ __launch_bounds__(256) void prep_kernel(
    const float* __restrict__ Q,        // [NQ][HD]
    const float* __restrict__ probes,   // [NB][HD]
    const float* __restrict__ angles,   // [NF]
    const float* __restrict__ qw,       // [NB][NF]
    const float* __restrict__ mw,       // [NB][NF]
    f32x4* __restrict__ qA,             // [NFP][NQ]
    FP2Row* __restrict__ tab) {         // [NBT][NFP]
    __shared__ f32x4 sA[8][NFP + 1];    // +1: dodge bank conflicts
    if (blockIdx.x < 2048) {
        // 8 q per block, half-wave (32 lanes) per q; lane sl owns f-pair sl.
        const int qi = threadIdx.x >> 5;
        const int sl = threadIdx.x & 31;
        const int q  = blockIdx.x * 8 + qi;
        const float2* Q2 = (const float2*)Q;
        float2 a = Q2[q * 64 + sl];        // Qr[2sl], Qr[2sl+1]
        float2 c = Q2[q * 64 + 32 + sl];   // Qi[2sl], Qi[2sl+1]
        float ss = a.x * a.x + a.y * a.y + c.x * c.x + c.y * c.y;
        #pragma unroll
        for (int m = 1; m < 32; m <<= 1) ss += __shfl_xor(ss, m);  // half-wave
        float inv = 1.0f / (sqrtf(ss) + EPSF);
        f32x4 Av;
        Av.x = a.x * inv; Av.y = a.y * inv;   // Qr0, Qr1
        Av.z = c.x * inv; Av.w = c.y * inv;   // Qi0, Qi1
        sA[qi][sl] = Av;
        __syncthreads();
        // transposed write-out: 8 consecutive lanes write 128 B contiguous
        const int sl2 = threadIdx.x >> 3;   // f-pair
        const int qi2 = threadIdx.x & 7;    // q within block
        const int qb  = blockIdx.x * 8;
        qA[sl2 * NQ + qb + qi2] = sA[qi2][sl2];
    } else {
        // table: 1 b per wave, lane = f (scatter stores; 32 blocks, negligible)
        const int b = (blockIdx.x - 2048) * 4 + (threadIdx.x >> 6);
        const int f = threadIdx.x & 63;
        float p0 = probes[b * HD + f];
        float p1 = probes[b * HD + 64 + f];
        float ss = p0 * p0 + p1 * p1;
        #pragma unroll
        for (int m = 1; m < 64; m <<= 1) ss += __shfl_xor(ss, m);
        float inv = 1.0f / (sqrtf(ss) + EPSF);
        float pr = p0 * inv, pi = p1 * inv;
        float ang = angles[f];
        float cc = cosf(ang), sn = sinf(ang);
        float Pr = pr * cc - pi * sn;
        float Pi = pr * sn + pi * cc;
        float x = qw[b * NF + f];
        float sp = (x > 0.0f) ? (x + log1pf(expf(-x))) : log1pf(expf(x));
        FP2Row* r = &tab[(b >> 3) * NFP + (f >> 1)];
        const int h  = f & 1;
        const int bb = b & 7;
        ((float*)&r->x2[bb])[h] = -2.0f * Pr;
        ((float*)&r->y2[bb])[h] = -2.0f * Pi;
        ((float*)&r->z2[bb])[h] = Pr * Pr + Pi * Pi + EPSF;
        ((float*)&r->w2[bb])[h] = -sp;
        ((float*)&r->m2[bb])[h] = mw[b * NF + f];
    }
}

// ---------- main kernel ----------
// Per fp per wave: was 2 KB streamed (qA+qB) vs 144 VALU cyc -> 57 B/cyc/CU
// demand == per-CU L2-return limit (the real round-0..3 bottleneck; VALUBusy
// stuck ~51% regardless of table path). Now 1 KB streamed vs ~158 VALU cyc
// (B and mag recomputed: +1 pk_mul +1 pk_fma +2 v_add +2 sqrt per fp) ->
// ~26 B/cyc/CU demand -> VALU-bound.
__global__ __launch_bounds__(256, 4) void main_kernel(
    const FP2Row* __restrict__ tab,     // [NBT][NFP]
    const f32x4* __restrict__ qA,       // [NFP][NQ]
    const float* __restrict__ bias,     // [NB]
    float* __restrict__ out) {          // [NQ][NB]
    // XCD-bijective swizzle: all 16 bt-blocks of one q-chunk on ONE XCD.
    const int p    = blockIdx.x;
    const int xcd  = p & 7;
    const int j    = p >> 3;                 // 0..127 per XCD
    const int qblk = xcd * 8 + (j >> 4);     // 0..63
    const int bt   = j & 15;
    const int q    = qblk * 256 + threadIdx.x;

    const FP2Row* __restrict__ tr = tab + bt * NFP;

    f32x2 acc[BTILE];
    #pragma unroll
    for (int i = 0; i < BTILE; ++i) acc[i] = 0.0f;

    // one-iteration register prefetch of the coalesced q-plane
    f32x4 A = qA[q];            // fp = 0
    for (int fp = 0; fp < NFP; ++fp) {
        const int fpn = (fp < NFP - 1) ? fp + 1 : fp;
        f32x4 An = qA[fpn * NQ + q];
        f32x2 qr2 = __builtin_shufflevector(A, A, 0, 1);
        f32x2 qi2 = __builtin_shufflevector(A, A, 2, 3);
        f32x2 qz2 = qr2 * qr2;                              // B = Qr^2+Qi^2
        qz2 = __builtin_elementwise_fma(qi2, qi2, qz2);
        f32x2 qm2;                                          // mag = sqrt(B+eps)
        qm2.x = __builtin_amdgcn_sqrtf(qz2.x + EPSF);
        qm2.y = __builtin_amdgcn_sqrtf(qz2.y + EPSF);
        const FP2Row* r = tr + fp;
        #pragma unroll
        for (int bb = 0; bb < BTILE; ++bb) {
            f32x2 t = r->z2[bb] + qz2;                          // v_pk_add_f32
            t = __builtin_elementwise_fma(r->y2[bb], qi2, t);   // v_pk_fma_f32
            t = __builtin_elementwise_fma(r->x2[bb], qr2, t);
            f32x2 d;
            d.x = __builtin_amdgcn_sqrtf(__builtin_fabsf(t.x)); // |t| = src mod
            d.y = __builtin_amdgcn_sqrtf(__builtin_fabsf(t.y));
            acc[bb] = __builtin_elementwise_fma(r->w2[bb], d, acc[bb]);
            acc[bb] = __builtin_elementwise_fma(r->m2[bb], qm2, acc[bb]);
        }
        A = An;
    }

    float o[BTILE];
    #pragma unroll
    for (int bb = 0; bb < BTILE; ++bb)
        o[bb] = acc[bb].x + acc[bb].y + bias[bt * BTILE + bb];
    float* op = out + (size_t)q * NB + bt * BTILE;
    *(float4*)op       = make_float4(o[0], o[1], o[2], o[3]);
    *(float4*)(op + 4) = make_float4(o[4], o[5], o[6], o[7]);
}

extern "C" void kernel_launch(void* const* d_in, const int* in_sizes, int n_in,
                              void* d_out, int out_size, void* d_ws, size_t ws_size,
                              hipStream_t stream) {
    const float* Q      = (const float*)d_in[0];   // [16384][128]
    const float* angles = (const float*)d_in[1];   // [64]
    const float* probes = (const float*)d_in[2];   // [128][128]
    const float* qw     = (const float*)d_in[3];   // [128][64]
    const float* mw     = (const float*)d_in[4];   // [128][64]
    const float* bias   = (const float*)d_in[5];   // [128]
    float* out = (float*)d_out;

    char* ws = (char*)d_ws;
    FP2Row* tab = (FP2Row*)ws;                                   // 160 KB
    f32x4*  qA  = (f32x4*)(ws + NBT * NFP * sizeof(FP2Row));     // 8 MB

    prep_kernel<<<2048 + NB / 4, 256, 0, stream>>>(Q, probes, angles, qw, mw, qA, tab);
    main_kernel<<<(NQ / 256) * NBT, 256, 0, stream>>>(tab, qA, bias, out);
}